// Round 3
// baseline (506.509 us; speedup 1.0000x reference)
//
#include <hip/hip_runtime.h>
#include <hip/hip_bf16.h>

#define B_ 32
#define S_ 512
#define H_ 768
#define NH_ 12
#define DH_ 64
#define EC_ 4
#define CAPN_ 8

using short8  = __attribute__((ext_vector_type(8))) short;
using floatx4 = __attribute__((ext_vector_type(4))) float;
using bf16 = __hip_bfloat16;

// async 16B global->LDS. LDS dest must be wave-uniform base + lane*16.
__device__ __forceinline__ void gl_lds16(const void* g, void* l) {
  __builtin_amdgcn_global_load_lds(
      (const __attribute__((address_space(1))) unsigned int*)g,
      (__attribute__((address_space(3))) unsigned int*)l, 16, 0, 0);
}

// ---------- kernel 1: partial sums over S (8 chunks of 64) + fp32->bf16 convert ----------
__global__ void k_mean_convert(const float* __restrict__ X, bf16* __restrict__ Xh,
                               float* __restrict__ partial) {
  int idx = blockIdx.x * 256 + threadIdx.x;          // (b,h) 0..24575
  int b = idx / H_, h = idx - b * H_;
  int s0 = blockIdx.y * 64;
  size_t base = ((size_t)b * S_ + s0) * H_ + h;
  float sum = 0.f;
#pragma unroll 8
  for (int s = 0; s < 64; ++s) {
    float v = X[base + (size_t)s * H_];
    Xh[base + (size_t)s * H_] = __float2bfloat16(v);
    sum += v;
  }
  partial[(size_t)blockIdx.y * (B_ * H_) + idx] = sum;
}

__global__ void k_mean_reduce(const float* __restrict__ partial, float* __restrict__ hmean) {
  int idx = blockIdx.x * 256 + threadIdx.x;
  float s = 0.f;
#pragma unroll
  for (int c = 0; c < 8; ++c) s += partial[(size_t)c * (B_ * H_) + idx];
  hmean[idx] = s * (1.f / 512.f);                    // 1/512 exact
}

// ---------- kernel 2: W[k][n] -> Wt[n][k] bf16, all 4 mats x 8 experts ----------
__global__ void k_wt(const float* __restrict__ Wq, const float* __restrict__ Wk,
                     const float* __restrict__ Wv, const float* __restrict__ Wo,
                     bf16* __restrict__ Wt) {
  __shared__ float tile[32][33];
  int z = blockIdx.z;
  const float* Wbase = (z < 8 ? Wq : z < 16 ? Wk : z < 24 ? Wv : Wo) + (size_t)(z & 7) * H_ * H_;
  int k0 = blockIdx.x * 32, n0 = blockIdx.y * 32;
  int tj = threadIdx.x & 31, ti = threadIdx.x >> 5;  // ti 0..7
#pragma unroll
  for (int r = 0; r < 4; ++r)
    tile[ti + r * 8][tj] = Wbase[(size_t)(k0 + ti + r * 8) * H_ + n0 + tj];
  __syncthreads();
  bf16* out = Wt + (size_t)z * H_ * H_;
#pragma unroll
  for (int r = 0; r < 4; ++r)
    out[(size_t)(n0 + ti + r * 8) * H_ + k0 + tj] = __float2bfloat16(tile[tj][ti + r * 8]);
}

// ---------- routing: gate logits (parallel) + tiny sort ----------
__global__ void k_gate(const float* __restrict__ hmean,
                       const float* __restrict__ Wsc, const float* __restrict__ bsc,
                       const float* __restrict__ Wsu, const float* __restrict__ bsu,
                       float* __restrict__ logits) {
  int b = blockIdx.x;
  int t = threadIdx.x;                               // 64 = 8 gates x 8 partials
  int g = t >> 3, p = t & 7;
  const float* hm = hmean + (size_t)b * H_;
  const float* w;
  float bias;
  if (g < 4) { w = Wsc + g; bias = bsc[g]; }
  else       { w = Wsu + (g - 4); bias = bsu[g - 4]; }
  float acc = 0.f;
  for (int j = p; j < H_; j += 8) acc += hm[j] * w[j * 4];
  acc += __shfl_xor(acc, 1);
  acc += __shfl_xor(acc, 2);
  acc += __shfl_xor(acc, 4);
  if (p == 0) logits[b * 8 + g] = acc + bias;
}

__global__ void k_route2(const float* __restrict__ logits, int* __restrict__ eidx) {
  __shared__ float pcmax[B_];
  __shared__ int rc_s[B_], ru_s[B_];
  int t = threadIdx.x;
  if (t < B_) {
    float lg[8];
#pragma unroll
    for (int e = 0; e < 8; ++e) lg[e] = logits[t * 8 + e];
    float m = lg[0]; int a = 0;                      // first-max ties like jnp.argmax
    for (int e = 1; e < 4; ++e) if (lg[e] > m) { m = lg[e]; a = e; }
    float s = 0.f;
    for (int e = 0; e < 4; ++e) s += expf(lg[e] - m);
    pcmax[t] = 1.f / s;                              // softmax max prob
    rc_s[t] = a;
    float mu = lg[4]; int au = 0;
    for (int e = 1; e < 4; ++e) if (lg[4 + e] > mu) { mu = lg[4 + e]; au = e; }
    ru_s[t] = au;
  }
  __syncthreads();
  if (t == 0) {
    // stable descending selection (equal -> lower index first) == argsort(-p)
    bool used[B_], kept[B_];
    int cnt[EC_] = {0, 0, 0, 0};
    for (int i = 0; i < B_; ++i) used[i] = false;
    for (int i = 0; i < B_; ++i) {
      int best = 0; float bv = -1e30f;
      for (int j = 0; j < B_; ++j)
        if (!used[j] && pcmax[j] > bv) { bv = pcmax[j]; best = j; }
      used[best] = true;
      kept[best] = (++cnt[rc_s[best]] <= CAPN_);
    }
    for (int i = 0; i < B_; ++i)
      eidx[i] = kept[i] ? rc_s[i] : EC_ + ru_s[i];
  }
}

// ---------- GEMM: Y[m][n] = sum_k A[m][k]*Wt[n][k] + bias[n] ----------
// 128x128 tile, BK=64, 256 thr (4 waves of 64x64), XOR-swizzled LDS chunks.
// OMODE 0: bf16 out (QKV; bz==2 writes V directly in Vt chunk layout)
// OMODE 1: fp32 out.
template <int OMODE>
__global__ __launch_bounds__(256) void k_gemm(
    const bf16* __restrict__ A, const bf16* __restrict__ Wt,
    const float* __restrict__ bias0, const float* __restrict__ bias1,
    const float* __restrict__ bias2,
    void* out0, void* out1, void* out2,
    const int* __restrict__ eidx, int mat0) {
  __shared__ __align__(16) char lds[32768];          // A tile 16KB | B tile 16KB
  int bz = blockIdx.z;
  int b = blockIdx.y;
  int e = eidx[b];
  int mtile = blockIdx.x & 3, ntile = blockIdx.x >> 2;
  int m0 = mtile * 128, n0 = ntile * 128;
  const bf16* Ab = A + (size_t)b * S_ * H_;
  const bf16* Wb = Wt + (size_t)((mat0 + bz) * 8 + e) * H_ * H_;
  const float* bias = ((bz == 0) ? bias0 : (bz == 1) ? bias1 : bias2) + (size_t)e * H_;
  void* outp = (bz == 0) ? out0 : (bz == 1) ? out1 : out2;

  int t = threadIdx.x, lane = t & 63, w = t >> 6;
  int wm = (w & 1) * 64, wn = (w >> 1) * 64;
  int lm = lane & 15, lq = lane >> 4;

  floatx4 acc[4][4] = {};
  for (int kt = 0; kt < 12; ++kt) {
    __syncthreads();                                 // protect LDS vs prev iter readers
#pragma unroll
    for (int r = 0; r < 8; ++r) {                    // 2048 chunks of 16B
      int c = t + r * 256;
      const bf16* g;
      if (c < 1024) {
        int mm = c >> 3, pos = c & 7, kc = pos ^ (mm & 7);
        g = Ab + (size_t)(m0 + mm) * H_ + kt * 64 + kc * 8;
      } else {
        int c2 = c - 1024;
        int nn = c2 >> 3, pos = c2 & 7, kc = pos ^ (nn & 7);
        g = Wb + (size_t)(n0 + nn) * H_ + kt * 64 + kc * 8;
      }
      gl_lds16(g, lds + (size_t)c * 16);
    }
    __syncthreads();                                 // vmcnt drained before barrier
#pragma unroll
    for (int kf = 0; kf < 2; ++kf) {
      int kc = kf * 4 + lq;
      short8 af[4], bf[4];
#pragma unroll
      for (int mf = 0; mf < 4; ++mf) {
        int mm = wm + mf * 16 + lm;
        af[mf] = *(const short8*)(lds + ((size_t)(mm * 8 + (kc ^ (mm & 7)))) * 16);
      }
#pragma unroll
      for (int nf = 0; nf < 4; ++nf) {
        int nn = wn + nf * 16 + lm;
        bf[nf] = *(const short8*)(lds + 16384 + ((size_t)(nn * 8 + (kc ^ (nn & 7)))) * 16);
      }
#pragma unroll
      for (int mf = 0; mf < 4; ++mf)
#pragma unroll
        for (int nf = 0; nf < 4; ++nf)
          acc[mf][nf] = __builtin_amdgcn_mfma_f32_16x16x32_bf16(af[mf], bf[nf], acc[mf][nf], 0, 0, 0);
    }
  }
  // epilogue: C/D layout col=lane&15, row=quad*4+reg
#pragma unroll
  for (int mf = 0; mf < 4; ++mf) {
#pragma unroll
    for (int nf = 0; nf < 4; ++nf) {
      int n = n0 + wn + nf * 16 + lm;
      float bv = bias[n];
      int mrow = m0 + wm + mf * 16 + lq * 4;
      size_t rowbase = ((size_t)b * S_ + mrow) * H_ + n;
#pragma unroll
      for (int r = 0; r < 4; ++r) {
        float v = acc[mf][nf][r] + bv;
        if (OMODE == 0) {
          if (bz == 2) {
            // V: write directly in Vt chunk layout [b*NH+h][s>>3][dh][s&7]
            int s = mrow + r;
            ((bf16*)outp)[((size_t)(b * NH_ + (n >> 6))) * 32768 +
                          (size_t)(s >> 3) * 512 + (n & 63) * 8 + (s & 7)] =
                __float2bfloat16(v);
          } else {
            ((bf16*)outp)[rowbase + (size_t)r * H_] = __float2bfloat16(v);
          }
        } else {
          ((float*)outp)[rowbase + (size_t)r * H_] = v;
        }
      }
    }
  }
}

// ---------- attention: barrier-free flash. Block = 4 waves x 32 q-rows, one (b,h). ----------
// All K / Vt operands loaded directly from global as MFMA B-frags (L1-served,
// reused across the 4 waves). P C->A layout transform via per-wave private LDS
// (row stride 72 + lq-xor swizzle: writes & b128 reads both ~2-way = free).
// No __syncthreads anywhere -> compiler pipelines loads across K-tiles.
__global__ __launch_bounds__(256, 3) void k_attn(
    const bf16* __restrict__ Q, const bf16* __restrict__ K,
    const bf16* __restrict__ Vt, const float* __restrict__ mask,
    bf16* __restrict__ Ctx) {
  __shared__ __align__(16) bf16 ldsP[4][32 * 72];    // per-wave P patch, 18.4 KB total

  int h = blockIdx.y, b = blockIdx.z;
  int t = threadIdx.x, lane = t & 63, w = t >> 6;
  int lm = lane & 15, lq = lane >> 4;
  int q0 = blockIdx.x * 128 + w * 32;                // this wave's 32 q-rows

  // Q A-frags (one-shot from global)
  short8 qf[2][2];
#pragma unroll
  for (int mf = 0; mf < 2; ++mf)
#pragma unroll
    for (int kf = 0; kf < 2; ++kf)
      qf[mf][kf] = *(const short8*)(Q + ((size_t)(b * S_ + q0 + mf * 16 + lm)) * H_ +
                                    h * DH_ + kf * 32 + lq * 8);

  const bf16* vtb = Vt + ((size_t)(b * NH_ + h)) * 32768;
  bf16* myP = ldsP[w];

  floatx4 oacc[2][4] = {};                           // O: rows (mf,lq,r) x dh cols (nf,lm)
  float m_[2][4], l_[2][4];
#pragma unroll
  for (int mf = 0; mf < 2; ++mf)
#pragma unroll
    for (int r = 0; r < 4; ++r) { m_[mf][r] = -1e30f; l_[mf][r] = 0.f; }

  for (int kt = 0; kt < 8; ++kt) {
    // ---- S = Q K^T : K B-frags straight from global ----
    floatx4 s[2][4] = {};
    float mv4[4];
#pragma unroll
    for (int nf = 0; nf < 4; ++nf)
      mv4[nf] = mask[(size_t)b * S_ + kt * 64 + nf * 16 + lm];
#pragma unroll
    for (int kf = 0; kf < 2; ++kf) {
      short8 kb4[4];
#pragma unroll
      for (int nf = 0; nf < 4; ++nf)
        kb4[nf] = *(const short8*)(K + ((size_t)(b * S_ + kt * 64 + nf * 16 + lm)) * H_ +
                                   h * DH_ + kf * 32 + lq * 8);
#pragma unroll
      for (int mf = 0; mf < 2; ++mf)
#pragma unroll
        for (int nf = 0; nf < 4; ++nf)
          s[mf][nf] = __builtin_amdgcn_mfma_f32_16x16x32_bf16(qf[mf][kf], kb4[nf], s[mf][nf], 0, 0, 0);
    }
    // ---- online softmax update (rows = mf*16 + lq*4 + r) ----
#pragma unroll
    for (int mf = 0; mf < 2; ++mf) {
#pragma unroll
      for (int r = 0; r < 4; ++r) {
#pragma unroll
        for (int nf = 0; nf < 4; ++nf)
          s[mf][nf][r] = s[mf][nf][r] * 0.125f + mv4[nf];
        float tm = fmaxf(fmaxf(s[mf][0][r], s[mf][1][r]), fmaxf(s[mf][2][r], s[mf][3][r]));
        tm = fmaxf(tm, __shfl_xor(tm, 1));
        tm = fmaxf(tm, __shfl_xor(tm, 2));
        tm = fmaxf(tm, __shfl_xor(tm, 4));
        tm = fmaxf(tm, __shfl_xor(tm, 8));
        float mn = fmaxf(m_[mf][r], tm);
        float a = __expf(m_[mf][r] - mn);
        m_[mf][r] = mn;
        int row = mf * 16 + lq * 4 + r;
        float ps = 0.f;
#pragma unroll
        for (int nf = 0; nf < 4; ++nf) {
          float p = __expf(s[mf][nf][r] - mn);
          ps += p;
          int col = (nf * 16 + lm) ^ (lq << 3);      // writer xor = (row>>2)&3 == lq
          myP[row * 72 + col] = __float2bfloat16(p);
        }
        ps += __shfl_xor(ps, 1);
        ps += __shfl_xor(ps, 2);
        ps += __shfl_xor(ps, 4);
        ps += __shfl_xor(ps, 8);
        l_[mf][r] = l_[mf][r] * a + ps;
#pragma unroll
        for (int nf = 0; nf < 4; ++nf) oacc[mf][nf][r] *= a;
      }
    }
    // ---- O += P V : P A-frags from private LDS, V B-frags from global Vt ----
#pragma unroll
    for (int kf = 0; kf < 2; ++kf) {
      short8 pf[2];
#pragma unroll
      for (int mf = 0; mf < 2; ++mf) {
        int row = mf * 16 + lm;
        int ksw = (kf * 32 + lq * 8) ^ ((((row >> 2) & 3)) << 3);
        pf[mf] = *(const short8*)&myP[row * 72 + ksw];
      }
      short8 vf4[4];
#pragma unroll
      for (int nf = 0; nf < 4; ++nf)
        vf4[nf] = *(const short8*)(vtb + ((size_t)(kt * 8 + kf * 4 + lq)) * 512 +
                                   (nf * 16 + lm) * 8);
#pragma unroll
      for (int mf = 0; mf < 2; ++mf)
#pragma unroll
        for (int nf = 0; nf < 4; ++nf)
          oacc[mf][nf] = __builtin_amdgcn_mfma_f32_16x16x32_bf16(pf[mf], vf4[nf], oacc[mf][nf], 0, 0, 0);
    }
  }
  // ---- epilogue: O / l ----
#pragma unroll
  for (int mf = 0; mf < 2; ++mf) {
#pragma unroll
    for (int r = 0; r < 4; ++r) {
      float inv = 1.f / l_[mf][r];
      int row = q0 + mf * 16 + lq * 4 + r;
#pragma unroll
      for (int nf = 0; nf < 4; ++nf)
        Ctx[((size_t)(b * S_ + row)) * H_ + h * DH_ + nf * 16 + lm] =
            __float2bfloat16(oacc[mf][nf][r] * inv);
    }
  }
}

extern "C" void kernel_launch(void* const* d_in, const int* in_sizes, int n_in,
                              void* d_out, int out_size, void* d_ws, size_t ws_size,
                              hipStream_t stream) {
  const float* X    = (const float*)d_in[0];
  const float* mask = (const float*)d_in[1];
  const float* Wq   = (const float*)d_in[2];
  const float* bq   = (const float*)d_in[3];
  const float* Wk   = (const float*)d_in[4];
  const float* bk   = (const float*)d_in[5];
  const float* Wv   = (const float*)d_in[6];
  const float* bv   = (const float*)d_in[7];
  const float* Wo   = (const float*)d_in[8];
  const float* bo   = (const float*)d_in[9];
  const float* Wsc  = (const float*)d_in[10];
  const float* bsc  = (const float*)d_in[11];
  const float* Wsu  = (const float*)d_in[12];
  const float* bsu  = (const float*)d_in[13];

  char* ws = (char*)d_ws;
  int*   eidx    = (int*)ws;                        //       128 B @ 0
  float* logits  = (float*)(ws + 128);              //     1,024 B
  float* partial = (float*)(ws + 1280);             //   786,432 B
  float* hmean   = (float*)(ws + 787712);           //    98,304 B
  bf16*  Xh      = (bf16*)(ws + 886016);            // 25,165,824 B
  bf16*  Wt      = (bf16*)(ws + 26051840);          // 37,748,736 B
  bf16*  qb      = (bf16*)(ws + 63800576);          // 25,165,824 B
  bf16*  kb      = (bf16*)(ws + 88966400);          // 25,165,824 B
  bf16*  Vt      = (bf16*)(ws + 114132224);         // 25,165,824 B -> 139,298,048 total
  bf16*  ctx     = Xh;                              // alias: Xh dead after QKV GEMM

  k_mean_convert<<<dim3(96, 8), 256, 0, stream>>>(X, Xh, partial);
  k_mean_reduce<<<96, 256, 0, stream>>>(partial, hmean);
  k_wt<<<dim3(24, 24, 32), 256, 0, stream>>>(Wq, Wk, Wv, Wo, Wt);
  k_gate<<<B_, 64, 0, stream>>>(hmean, Wsc, bsc, Wsu, bsu, logits);
  k_route2<<<1, 64, 0, stream>>>(logits, eidx);
  k_gemm<0><<<dim3(24, 32, 3), 256, 0, stream>>>(Xh, Wt, bq, bk, bv,
                                                 (void*)qb, (void*)kb, (void*)Vt, eidx, 0);
  k_attn<<<dim3(4, NH_, B_), 256, 0, stream>>>(qb, kb, Vt, mask, ctx);
  k_gemm<1><<<dim3(24, 32, 1), 256, 0, stream>>>(ctx, Wt, bo, bo, bo,
                                                 d_out, d_out, d_out, eidx, 3);
}

// Round 4
// 486.951 us; speedup vs baseline: 1.0402x; 1.0402x over previous
//
#include <hip/hip_runtime.h>
#include <hip/hip_bf16.h>

#define B_ 32
#define S_ 512
#define H_ 768
#define NH_ 12
#define DH_ 64
#define EC_ 4
#define CAPN_ 8

using short8  = __attribute__((ext_vector_type(8))) short;
using floatx4 = __attribute__((ext_vector_type(4))) float;
using bf16 = __hip_bfloat16;

// async 16B global->LDS. LDS dest must be wave-uniform base + lane*16.
__device__ __forceinline__ void gl_lds16(const void* g, void* l) {
  __builtin_amdgcn_global_load_lds(
      (const __attribute__((address_space(1))) unsigned int*)g,
      (__attribute__((address_space(3))) unsigned int*)l, 16, 0, 0);
}

// ---------- kernel 1: partial sums over S (8 chunks of 64) + fp32->bf16 convert ----------
__global__ void k_mean_convert(const float* __restrict__ X, bf16* __restrict__ Xh,
                               float* __restrict__ partial) {
  int idx = blockIdx.x * 256 + threadIdx.x;          // (b,h) 0..24575
  int b = idx / H_, h = idx - b * H_;
  int s0 = blockIdx.y * 64;
  size_t base = ((size_t)b * S_ + s0) * H_ + h;
  float sum = 0.f;
#pragma unroll 8
  for (int s = 0; s < 64; ++s) {
    float v = X[base + (size_t)s * H_];
    Xh[base + (size_t)s * H_] = __float2bfloat16(v);
    sum += v;
  }
  partial[(size_t)blockIdx.y * (B_ * H_) + idx] = sum;
}

__global__ void k_mean_reduce(const float* __restrict__ partial, float* __restrict__ hmean) {
  int idx = blockIdx.x * 256 + threadIdx.x;
  float s = 0.f;
#pragma unroll
  for (int c = 0; c < 8; ++c) s += partial[(size_t)c * (B_ * H_) + idx];
  hmean[idx] = s * (1.f / 512.f);                    // 1/512 exact
}

// ---------- kernel 2: W[k][n] -> Wt[n][k] bf16, all 4 mats x 8 experts ----------
__global__ void k_wt(const float* __restrict__ Wq, const float* __restrict__ Wk,
                     const float* __restrict__ Wv, const float* __restrict__ Wo,
                     bf16* __restrict__ Wt) {
  __shared__ float tile[32][33];
  int z = blockIdx.z;
  const float* Wbase = (z < 8 ? Wq : z < 16 ? Wk : z < 24 ? Wv : Wo) + (size_t)(z & 7) * H_ * H_;
  int k0 = blockIdx.x * 32, n0 = blockIdx.y * 32;
  int tj = threadIdx.x & 31, ti = threadIdx.x >> 5;  // ti 0..7
#pragma unroll
  for (int r = 0; r < 4; ++r)
    tile[ti + r * 8][tj] = Wbase[(size_t)(k0 + ti + r * 8) * H_ + n0 + tj];
  __syncthreads();
  bf16* out = Wt + (size_t)z * H_ * H_;
#pragma unroll
  for (int r = 0; r < 4; ++r)
    out[(size_t)(n0 + ti + r * 8) * H_ + k0 + tj] = __float2bfloat16(tile[tj][ti + r * 8]);
}

// ---------- routing: gate logits (parallel) + tiny sort ----------
__global__ void k_gate(const float* __restrict__ hmean,
                       const float* __restrict__ Wsc, const float* __restrict__ bsc,
                       const float* __restrict__ Wsu, const float* __restrict__ bsu,
                       float* __restrict__ logits) {
  int b = blockIdx.x;
  int t = threadIdx.x;                               // 64 = 8 gates x 8 partials
  int g = t >> 3, p = t & 7;
  const float* hm = hmean + (size_t)b * H_;
  const float* w;
  float bias;
  if (g < 4) { w = Wsc + g; bias = bsc[g]; }
  else       { w = Wsu + (g - 4); bias = bsu[g - 4]; }
  float acc = 0.f;
  for (int j = p; j < H_; j += 8) acc += hm[j] * w[j * 4];
  acc += __shfl_xor(acc, 1);
  acc += __shfl_xor(acc, 2);
  acc += __shfl_xor(acc, 4);
  if (p == 0) logits[b * 8 + g] = acc + bias;
}

__global__ void k_route2(const float* __restrict__ logits, int* __restrict__ eidx) {
  __shared__ float pcmax[B_];
  __shared__ int rc_s[B_], ru_s[B_];
  int t = threadIdx.x;
  if (t < B_) {
    float lg[8];
#pragma unroll
    for (int e = 0; e < 8; ++e) lg[e] = logits[t * 8 + e];
    float m = lg[0]; int a = 0;                      // first-max ties like jnp.argmax
    for (int e = 1; e < 4; ++e) if (lg[e] > m) { m = lg[e]; a = e; }
    float s = 0.f;
    for (int e = 0; e < 4; ++e) s += expf(lg[e] - m);
    pcmax[t] = 1.f / s;                              // softmax max prob
    rc_s[t] = a;
    float mu = lg[4]; int au = 0;
    for (int e = 1; e < 4; ++e) if (lg[4 + e] > mu) { mu = lg[4 + e]; au = e; }
    ru_s[t] = au;
  }
  __syncthreads();
  if (t == 0) {
    // stable descending selection (equal -> lower index first) == argsort(-p)
    bool used[B_], kept[B_];
    int cnt[EC_] = {0, 0, 0, 0};
    for (int i = 0; i < B_; ++i) used[i] = false;
    for (int i = 0; i < B_; ++i) {
      int best = 0; float bv = -1e30f;
      for (int j = 0; j < B_; ++j)
        if (!used[j] && pcmax[j] > bv) { bv = pcmax[j]; best = j; }
      used[best] = true;
      kept[best] = (++cnt[rc_s[best]] <= CAPN_);
    }
    for (int i = 0; i < B_; ++i)
      eidx[i] = kept[i] ? rc_s[i] : EC_ + ru_s[i];
  }
}

// ---------- GEMM: Y[m][n] = sum_k A[m][k]*Wt[n][k] + bias[n] ----------
// 128x128 tile, BK=64, 256 thr (4 waves of 64x64), XOR-swizzled LDS chunks.
// Double-buffered staging, ONE barrier per K-tile: prefetch(kt+1) issued BEFORE
// compute(kt) so the end-of-iter vmcnt drain is overlapped by the MFMA phase.
// OMODE 0: bf16 out (QKV; bz==2 writes V directly in Vt chunk layout)
// OMODE 1: fp32 out.
template <int OMODE>
__global__ __launch_bounds__(256) void k_gemm(
    const bf16* __restrict__ A, const bf16* __restrict__ Wt,
    const float* __restrict__ bias0, const float* __restrict__ bias1,
    const float* __restrict__ bias2,
    void* out0, void* out1, void* out2,
    const int* __restrict__ eidx, int mat0) {
  __shared__ __align__(16) char lds[2][32768];       // [buf][A 16KB | B 16KB]
  int bz = blockIdx.z;
  int b = blockIdx.y;
  int e = eidx[b];
  int mtile = blockIdx.x & 3, ntile = blockIdx.x >> 2;
  int m0 = mtile * 128, n0 = ntile * 128;
  const bf16* Ab = A + (size_t)b * S_ * H_;
  const bf16* Wb = Wt + (size_t)((mat0 + bz) * 8 + e) * H_ * H_;
  const float* bias = ((bz == 0) ? bias0 : (bz == 1) ? bias1 : bias2) + (size_t)e * H_;
  void* outp = (bz == 0) ? out0 : (bz == 1) ? out1 : out2;

  int t = threadIdx.x, lane = t & 63, w = t >> 6;
  int wm = (w & 1) * 64, wn = (w >> 1) * 64;
  int lm = lane & 15, lq = lane >> 4;

  auto stage = [&](int kt) {
    char* buf = lds[kt & 1];
#pragma unroll
    for (int r = 0; r < 8; ++r) {                    // 2048 chunks of 16B
      int c = t + r * 256;
      const bf16* g;
      if (c < 1024) {
        int mm = c >> 3, pos = c & 7, kc = pos ^ (mm & 7);
        g = Ab + (size_t)(m0 + mm) * H_ + kt * 64 + kc * 8;
      } else {
        int c2 = c - 1024;
        int nn = c2 >> 3, pos = c2 & 7, kc = pos ^ (nn & 7);
        g = Wb + (size_t)(n0 + nn) * H_ + kt * 64 + kc * 8;
      }
      gl_lds16(g, buf + (size_t)c * 16);
    }
  };

  floatx4 acc[4][4] = {};
  stage(0);
  __syncthreads();                                   // prologue: tile 0 ready
  for (int kt = 0; kt < 12; ++kt) {
    if (kt < 11) stage(kt + 1);                      // prefetch into other buffer
    const char* cur = lds[kt & 1];
#pragma unroll
    for (int kf = 0; kf < 2; ++kf) {
      int kc = kf * 4 + lq;
      short8 af[4], bf[4];
#pragma unroll
      for (int mf = 0; mf < 4; ++mf) {
        int mm = wm + mf * 16 + lm;
        af[mf] = *(const short8*)(cur + ((size_t)(mm * 8 + (kc ^ (mm & 7)))) * 16);
      }
#pragma unroll
      for (int nf = 0; nf < 4; ++nf) {
        int nn = wn + nf * 16 + lm;
        bf[nf] = *(const short8*)(cur + 16384 + ((size_t)(nn * 8 + (kc ^ (nn & 7)))) * 16);
      }
#pragma unroll
      for (int mf = 0; mf < 4; ++mf)
#pragma unroll
        for (int nf = 0; nf < 4; ++nf)
          acc[mf][nf] = __builtin_amdgcn_mfma_f32_16x16x32_bf16(af[mf], bf[nf], acc[mf][nf], 0, 0, 0);
    }
    if (kt < 11) __syncthreads();                    // drain prefetch (overlapped) + WAR
  }
  // epilogue: C/D layout col=lane&15, row=quad*4+reg
#pragma unroll
  for (int mf = 0; mf < 4; ++mf) {
#pragma unroll
    for (int nf = 0; nf < 4; ++nf) {
      int n = n0 + wn + nf * 16 + lm;
      float bv = bias[n];
      int mrow = m0 + wm + mf * 16 + lq * 4;
      size_t rowbase = ((size_t)b * S_ + mrow) * H_ + n;
#pragma unroll
      for (int r = 0; r < 4; ++r) {
        float v = acc[mf][nf][r] + bv;
        if (OMODE == 0) {
          if (bz == 2) {
            // V: write directly in Vt chunk layout [b*NH+h][s>>3][dh][s&7]
            int s = mrow + r;
            ((bf16*)outp)[((size_t)(b * NH_ + (n >> 6))) * 32768 +
                          (size_t)(s >> 3) * 512 + (n & 63) * 8 + (s & 7)] =
                __float2bfloat16(v);
          } else {
            ((bf16*)outp)[rowbase + (size_t)r * H_] = __float2bfloat16(v);
          }
        } else {
          ((float*)outp)[rowbase + (size_t)r * H_] = v;
        }
      }
    }
  }
}

// ---------- attention: barrier-free flash. Block = 4 waves x 32 q-rows, one (b,h). ----------
// All K / Vt operands loaded directly from global as MFMA B-frags (L1-served,
// reused across the 4 waves). P C->A layout transform via per-wave private LDS
// (row stride 72 + lq-xor swizzle: writes & b128 reads both ~2-way = free).
// No __syncthreads anywhere -> compiler pipelines loads across K-tiles.
__global__ __launch_bounds__(256, 3) void k_attn(
    const bf16* __restrict__ Q, const bf16* __restrict__ K,
    const bf16* __restrict__ Vt, const float* __restrict__ mask,
    bf16* __restrict__ Ctx) {
  __shared__ __align__(16) bf16 ldsP[4][32 * 72];    // per-wave P patch, 18.4 KB total

  int h = blockIdx.y, b = blockIdx.z;
  int t = threadIdx.x, lane = t & 63, w = t >> 6;
  int lm = lane & 15, lq = lane >> 4;
  int q0 = blockIdx.x * 128 + w * 32;                // this wave's 32 q-rows

  // Q A-frags (one-shot from global)
  short8 qf[2][2];
#pragma unroll
  for (int mf = 0; mf < 2; ++mf)
#pragma unroll
    for (int kf = 0; kf < 2; ++kf)
      qf[mf][kf] = *(const short8*)(Q + ((size_t)(b * S_ + q0 + mf * 16 + lm)) * H_ +
                                    h * DH_ + kf * 32 + lq * 8);

  const bf16* vtb = Vt + ((size_t)(b * NH_ + h)) * 32768;
  bf16* myP = ldsP[w];

  floatx4 oacc[2][4] = {};                           // O: rows (mf,lq,r) x dh cols (nf,lm)
  float m_[2][4], l_[2][4];
#pragma unroll
  for (int mf = 0; mf < 2; ++mf)
#pragma unroll
    for (int r = 0; r < 4; ++r) { m_[mf][r] = -1e30f; l_[mf][r] = 0.f; }

  for (int kt = 0; kt < 8; ++kt) {
    // ---- S = Q K^T : K B-frags straight from global ----
    floatx4 s[2][4] = {};
    float mv4[4];
#pragma unroll
    for (int nf = 0; nf < 4; ++nf)
      mv4[nf] = mask[(size_t)b * S_ + kt * 64 + nf * 16 + lm];
#pragma unroll
    for (int kf = 0; kf < 2; ++kf) {
      short8 kb4[4];
#pragma unroll
      for (int nf = 0; nf < 4; ++nf)
        kb4[nf] = *(const short8*)(K + ((size_t)(b * S_ + kt * 64 + nf * 16 + lm)) * H_ +
                                   h * DH_ + kf * 32 + lq * 8);
#pragma unroll
      for (int mf = 0; mf < 2; ++mf)
#pragma unroll
        for (int nf = 0; nf < 4; ++nf)
          s[mf][nf] = __builtin_amdgcn_mfma_f32_16x16x32_bf16(qf[mf][kf], kb4[nf], s[mf][nf], 0, 0, 0);
    }
    // ---- online softmax update (rows = mf*16 + lq*4 + r) ----
#pragma unroll
    for (int mf = 0; mf < 2; ++mf) {
#pragma unroll
      for (int r = 0; r < 4; ++r) {
#pragma unroll
        for (int nf = 0; nf < 4; ++nf)
          s[mf][nf][r] = s[mf][nf][r] * 0.125f + mv4[nf];
        float tm = fmaxf(fmaxf(s[mf][0][r], s[mf][1][r]), fmaxf(s[mf][2][r], s[mf][3][r]));
        tm = fmaxf(tm, __shfl_xor(tm, 1));
        tm = fmaxf(tm, __shfl_xor(tm, 2));
        tm = fmaxf(tm, __shfl_xor(tm, 4));
        tm = fmaxf(tm, __shfl_xor(tm, 8));
        float mn = fmaxf(m_[mf][r], tm);
        float a = __expf(m_[mf][r] - mn);
        m_[mf][r] = mn;
        int row = mf * 16 + lq * 4 + r;
        float ps = 0.f;
#pragma unroll
        for (int nf = 0; nf < 4; ++nf) {
          float p = __expf(s[mf][nf][r] - mn);
          ps += p;
          int col = (nf * 16 + lm) ^ (lq << 3);      // writer xor = (row>>2)&3 == lq
          myP[row * 72 + col] = __float2bfloat16(p);
        }
        ps += __shfl_xor(ps, 1);
        ps += __shfl_xor(ps, 2);
        ps += __shfl_xor(ps, 4);
        ps += __shfl_xor(ps, 8);
        l_[mf][r] = l_[mf][r] * a + ps;
#pragma unroll
        for (int nf = 0; nf < 4; ++nf) oacc[mf][nf][r] *= a;
      }
    }
    // ---- O += P V : P A-frags from private LDS, V B-frags from global Vt ----
#pragma unroll
    for (int kf = 0; kf < 2; ++kf) {
      short8 pf[2];
#pragma unroll
      for (int mf = 0; mf < 2; ++mf) {
        int row = mf * 16 + lm;
        int ksw = (kf * 32 + lq * 8) ^ ((((row >> 2) & 3)) << 3);
        pf[mf] = *(const short8*)&myP[row * 72 + ksw];
      }
      short8 vf4[4];
#pragma unroll
      for (int nf = 0; nf < 4; ++nf)
        vf4[nf] = *(const short8*)(vtb + ((size_t)(kt * 8 + kf * 4 + lq)) * 512 +
                                   (nf * 16 + lm) * 8);
#pragma unroll
      for (int mf = 0; mf < 2; ++mf)
#pragma unroll
        for (int nf = 0; nf < 4; ++nf)
          oacc[mf][nf] = __builtin_amdgcn_mfma_f32_16x16x32_bf16(pf[mf], vf4[nf], oacc[mf][nf], 0, 0, 0);
    }
  }
  // ---- epilogue: O / l ----
#pragma unroll
  for (int mf = 0; mf < 2; ++mf) {
#pragma unroll
    for (int r = 0; r < 4; ++r) {
      float inv = 1.f / l_[mf][r];
      int row = q0 + mf * 16 + lq * 4 + r;
#pragma unroll
      for (int nf = 0; nf < 4; ++nf)
        Ctx[((size_t)(b * S_ + row)) * H_ + h * DH_ + nf * 16 + lm] =
            __float2bfloat16(oacc[mf][nf][r] * inv);
    }
  }
}

extern "C" void kernel_launch(void* const* d_in, const int* in_sizes, int n_in,
                              void* d_out, int out_size, void* d_ws, size_t ws_size,
                              hipStream_t stream) {
  const float* X    = (const float*)d_in[0];
  const float* mask = (const float*)d_in[1];
  const float* Wq   = (const float*)d_in[2];
  const float* bq   = (const float*)d_in[3];
  const float* Wk   = (const float*)d_in[4];
  const float* bk   = (const float*)d_in[5];
  const float* Wv   = (const float*)d_in[6];
  const float* bv   = (const float*)d_in[7];
  const float* Wo   = (const float*)d_in[8];
  const float* bo   = (const float*)d_in[9];
  const float* Wsc  = (const float*)d_in[10];
  const float* bsc  = (const float*)d_in[11];
  const float* Wsu  = (const float*)d_in[12];
  const float* bsu  = (const float*)d_in[13];

  char* ws = (char*)d_ws;
  int*   eidx    = (int*)ws;                        //       128 B @ 0
  float* logits  = (float*)(ws + 128);              //     1,024 B
  float* partial = (float*)(ws + 1280);             //   786,432 B
  float* hmean   = (float*)(ws + 787712);           //    98,304 B
  bf16*  Xh      = (bf16*)(ws + 886016);            // 25,165,824 B
  bf16*  Wt      = (bf16*)(ws + 26051840);          // 37,748,736 B
  bf16*  qb      = (bf16*)(ws + 63800576);          // 25,165,824 B
  bf16*  kb      = (bf16*)(ws + 88966400);          // 25,165,824 B
  bf16*  Vt      = (bf16*)(ws + 114132224);         // 25,165,824 B -> 139,298,048 total
  bf16*  ctx     = Xh;                              // alias: Xh dead after QKV GEMM

  k_mean_convert<<<dim3(96, 8), 256, 0, stream>>>(X, Xh, partial);
  k_mean_reduce<<<96, 256, 0, stream>>>(partial, hmean);
  k_wt<<<dim3(24, 24, 32), 256, 0, stream>>>(Wq, Wk, Wv, Wo, Wt);
  k_gate<<<B_, 64, 0, stream>>>(hmean, Wsc, bsc, Wsu, bsu, logits);
  k_route2<<<1, 64, 0, stream>>>(logits, eidx);
  k_gemm<0><<<dim3(24, 32, 3), 256, 0, stream>>>(Xh, Wt, bq, bk, bv,
                                                 (void*)qb, (void*)kb, (void*)Vt, eidx, 0);
  k_attn<<<dim3(4, NH_, B_), 256, 0, stream>>>(qb, kb, Vt, mask, ctx);
  k_gemm<1><<<dim3(24, 32, 1), 256, 0, stream>>>(ctx, Wt, bo, bo, bo,
                                                 d_out, d_out, d_out, eidx, 3);
}